// Round 1
// baseline (358.780 us; speedup 1.0000x reference)
//
#include <hip/hip_runtime.h>
#include <stdint.h>
#include <math.h>

// Problem constants (fixed by setup_inputs: B=4, N=4096, H=2048, L=64, K=8)
constexpr int H     = 2048;
constexpr int L     = 64;
constexpr int K_SEL = 8;
constexpr int TM    = 64;   // rows per block
constexpr int BK    = 64;   // k-chunk per LDS stage
constexpr int S     = 68;   // padded stride (floats) for transposed LDS tiles (16B-aligned, conflict-light)
constexpr int LG_S  = 65;   // stride (doubles) for the logits grid in LDS

// fp64 accumulation: selected_heads requires exact top-8 index match vs the np
// reference; fp32 accumulation-order noise (~1e-6) vs typical rank-8 gaps
// (~0.07) would flip a few rows out of 16384. fp64 makes selection exact.
__global__ __launch_bounds__(256)
void router_main(const float* __restrict__ x,
                 const float* __restrict__ Wr,
                 const float* __restrict__ bias,
                 const unsigned char* __restrict__ am,
                 float* __restrict__ out_sel,
                 float* __restrict__ out_probs,
                 unsigned int* __restrict__ g_counts)
{
    // union: two fp32 tiles (2*BK*S*4 = 34816 B) overlap the fp64 logit grid (64*65*8 = 33280 B)
    __shared__ __align__(16) char smem_raw[BK * S * 2 * 4];
    float*  xs  = (float*)smem_raw;        // xs[k*S + r]
    float*  ws  = xs + BK * S;             // ws[k*S + c]
    double* lgd = (double*)smem_raw;       // lgd[row*LG_S + col]
    __shared__ float bs[L];
    __shared__ unsigned int cnt[L + 1];    // [L] = per-expert counts, [L] slot = active rows

    const int t  = threadIdx.x;
    const int R0 = blockIdx.x * TM;
    const int ty = t >> 4, tx = t & 15;
    const int r0 = ty * 4, c0 = tx * 4;

    if (t < L) bs[t] = bias[t];

    const int srow = t >> 4;            // staging row base 0..15
    const int skq  = (t & 15) << 2;     // staging k offset 0..60

    double acc[4][4];
    #pragma unroll
    for (int i = 0; i < 4; ++i)
        #pragma unroll
        for (int j = 0; j < 4; ++j) acc[i][j] = 0.0;

    // register-prefetch of the first tile (global latency overlaps compute thereafter)
    float4 xg[4], wg[4];
    #pragma unroll
    for (int i = 0; i < 4; ++i) {
        int row = srow + i * 16;
        xg[i] = *(const float4*)(x  + (size_t)(R0 + row) * H + skq);
        wg[i] = *(const float4*)(Wr + (size_t)row * H + skq);
    }

    for (int k0 = 0; k0 < H; k0 += BK) {
        // write prefetched tile into LDS, transposed to [k][row]
        #pragma unroll
        for (int i = 0; i < 4; ++i) {
            int row = srow + i * 16;
            float* xd = xs + skq * S + row;
            xd[0] = xg[i].x; xd[S] = xg[i].y; xd[2 * S] = xg[i].z; xd[3 * S] = xg[i].w;
            float* wd = ws + skq * S + row;
            wd[0] = wg[i].x; wd[S] = wg[i].y; wd[2 * S] = wg[i].z; wd[3 * S] = wg[i].w;
        }
        __syncthreads();

        // issue next tile's global loads early (hidden under the fp64 FMA loop)
        if (k0 + BK < H) {
            #pragma unroll
            for (int i = 0; i < 4; ++i) {
                int row = srow + i * 16;
                xg[i] = *(const float4*)(x  + (size_t)(R0 + row) * H + (k0 + BK + skq));
                wg[i] = *(const float4*)(Wr + (size_t)row * H + (k0 + BK + skq));
            }
        }

        #pragma unroll 8
        for (int k = 0; k < BK; ++k) {
            float4 xv = *(const float4*)(xs + k * S + r0);  // 4 rows at k (broadcast across tx)
            float4 wv = *(const float4*)(ws + k * S + c0);  // 4 cols at k (2-way = free)
            double xr[4] = {xv.x, xv.y, xv.z, xv.w};
            double wc[4] = {wv.x, wv.y, wv.z, wv.w};
            #pragma unroll
            for (int i = 0; i < 4; ++i)
                #pragma unroll
                for (int j = 0; j < 4; ++j)
                    acc[i][j] = fma(xr[i], wc[j], acc[i][j]);
        }
        __syncthreads();
    }

    // park logits (fp64) in LDS for the per-row epilogue
    #pragma unroll
    for (int i = 0; i < 4; ++i)
        #pragma unroll
        for (int j = 0; j < 4; ++j)
            lgd[(size_t)(r0 + i) * LG_S + (c0 + j)] = acc[i][j];
    if (t < L + 1) cnt[t] = 0;
    __syncthreads();

    if (t < TM) {
        const int grow = R0 + t;
        const double* row = lgd + (size_t)t * LG_S;   // stride-65 doubles: conflict-free per lane

        // top-8 by (logit + bias); strict '>' picks lowest index on ties == jax.lax.top_k
        unsigned long long chosen = 0ull;
        int idx[K_SEL];
        for (int kk = 0; kk < K_SEL; ++kk) {
            double best = -INFINITY; int bi = 0;
            for (int l = 0; l < L; ++l) {
                if ((chosen >> l) & 1ull) continue;
                double v = row[l] + (double)bs[l];
                if (v > best) { best = v; bi = l; }
            }
            chosen |= 1ull << bi;
            idx[kk] = bi;
        }

        // softmax denominator cancels under renormalization: probs = softmax over
        // the 8 selected *unbiased* logits
        double zv[K_SEL], mx = -INFINITY;
        #pragma unroll
        for (int kk = 0; kk < K_SEL; ++kk) { zv[kk] = row[idx[kk]]; mx = fmax(mx, zv[kk]); }
        float e[K_SEL], ssum = 0.f;
        #pragma unroll
        for (int kk = 0; kk < K_SEL; ++kk) { e[kk] = expf((float)(zv[kk] - mx)); ssum += e[kk]; }

        #pragma unroll
        for (int kk = 0; kk < K_SEL; ++kk) {
            out_sel[(size_t)grow * K_SEL + kk]   = (float)idx[kk];
            out_probs[(size_t)grow * K_SEL + kk] = e[kk] / ssum;
        }

        if (am[grow]) {
            atomicAdd(&cnt[L], 1u);
            #pragma unroll
            for (int kk = 0; kk < K_SEL; ++kk) atomicAdd(&cnt[idx[kk]], 1u);
        }
    }
    __syncthreads();
    if (t < L + 1 && cnt[t]) atomicAdd(&g_counts[t], cnt[t]);
}

__global__ void router_finalize(const unsigned int* __restrict__ g_counts,
                                float* __restrict__ out_scalars)
{
    const int l = threadIdx.x;  // 64 threads, one wave
    const float denom = (float)g_counts[L] * (float)K_SEL;  // num_active_assignments
    const float f = (float)g_counts[l] / denom;
    float d  = f - 1.0f / (float)L;
    float sq = d * d;
    #pragma unroll
    for (int o = 32; o > 0; o >>= 1) {
        sq += __shfl_down(sq, o);
        d = fmaxf(d, __shfl_down(d, o));
    }
    if (l == 0) {
        out_scalars[0] = (float)L * sq;  // load_balance_loss
        out_scalars[1] = (float)L * d;   // max_vio
    }
}

__global__ void zero_ws(unsigned int* p)
{
    if (threadIdx.x < L + 1) p[threadIdx.x] = 0u;  // d_ws is re-poisoned 0xAA each launch
}

extern "C" void kernel_launch(void* const* d_in, const int* in_sizes, int n_in,
                              void* d_out, int out_size, void* d_ws, size_t ws_size,
                              hipStream_t stream)
{
    const float* x          = (const float*)d_in[0];
    const float* Wr         = (const float*)d_in[1];
    const float* bias       = (const float*)d_in[2];
    const unsigned char* am = (const unsigned char*)d_in[3];  // bool array = 1 byte/elem
    float* out = (float*)d_out;
    unsigned int* counts = (unsigned int*)d_ws;

    const int rows = in_sizes[3];  // B*N = 16384

    float* out_sel   = out;
    float* out_probs = out + (size_t)rows * K_SEL;
    float* out_scal  = out + (size_t)rows * K_SEL * 2;

    hipLaunchKernelGGL(zero_ws,         dim3(1),         dim3(128), 0, stream, counts);
    hipLaunchKernelGGL(router_main,     dim3(rows / TM), dim3(256), 0, stream,
                       x, Wr, bias, am, out_sel, out_probs, counts);
    hipLaunchKernelGGL(router_finalize, dim3(1),         dim3(64),  0, stream, counts, out_scal);
}